// Round 7
// baseline (775.222 us; speedup 1.0000x reference)
//
#include <hip/hip_runtime.h>
#include <hip/hip_bf16.h>

#define NB 32
#define NT 1024
#define ND 512
#define NS 1024

#define CTX_ELEMS (32u * 1024u * 512u)          // 16777216
#define SP_SCRATCH_OFF (CTX_ELEMS - 32u*1024u)  // stash sp in contexts tail (overwritten later)

__device__ __forceinline__ float vlog2(float x) {
    float r; asm("v_log_f32 %0, %1" : "=v"(r) : "v"(x)); return r;
}
__device__ __forceinline__ float vexp2(float x) {
    float r; asm("v_exp_f32 %0, %1" : "=v"(r) : "v"(x)); return r;
}
__device__ __forceinline__ float vrcp(float x) {
    float r; asm("v_rcp_f32 %0, %1" : "=v"(r) : "v"(x)); return r;
}

template<int ctrl, int rm, int bm, bool bc>
__device__ __forceinline__ float dppadd(float x) {
    int y = __builtin_amdgcn_update_dpp(0, __float_as_int(x), ctrl, rm, bm, bc);
    return x + __int_as_float(y);
}
// full-wave sum; valid result lands in lane 63
__device__ __forceinline__ float reduce63(float x) {
    x = dppadd<0x111, 0xf, 0xf, true >(x);   // row_shr:1
    x = dppadd<0x112, 0xf, 0xf, true >(x);   // row_shr:2
    x = dppadd<0x114, 0xf, 0xf, true >(x);   // row_shr:4
    x = dppadd<0x118, 0xf, 0xf, true >(x);   // row_shr:8
    x = dppadd<0x142, 0xa, 0xf, false>(x);   // row_bcast:15
    x = dppadd<0x143, 0xc, 0xf, false>(x);   // row_bcast:31
    return x;
}
// lane L receives x from lane L-1 (lane 0 gets 0)
__device__ __forceinline__ float wave_shr1(float x) {
    int y = __builtin_amdgcn_update_dpp(0, __float_as_int(x), 0x138, 0xf, 0xf, true);
    return __int_as_float(y);
}

// barrier that waits ONLY on LDS ops — global stores stay in flight
__device__ __forceinline__ void lds_barrier() {
    asm volatile("s_waitcnt lgkmcnt(0)" ::: "memory");
    __builtin_amdgcn_s_barrier();
    asm volatile("" ::: "memory");
}

// ---------------- kernel 1: sp[b][t] = sigmoid(dot(x[b,t,:], W) + bias) ----------------
__global__ __launch_bounds__(256) void sp_kernel(const float* __restrict__ x,
                                                 const float* __restrict__ W,
                                                 const float* __restrict__ bias,
                                                 float* __restrict__ sp)
{
    const int lane = threadIdx.x & 63;
    const int wid  = threadIdx.x >> 6;
    const int row  = blockIdx.x * 4 + wid;          // b*NT + t
    const float4* xr = reinterpret_cast<const float4*>(x + (size_t)row * ND) + lane * 2;
    const float4* wr = reinterpret_cast<const float4*>(W) + lane * 2;
    float4 xa = xr[0], xb = xr[1];
    float4 wa = wr[0], wb = wr[1];
    float d = xa.x*wa.x + xa.y*wa.y + xa.z*wa.z + xa.w*wa.w
            + xb.x*wb.x + xb.y*wb.y + xb.z*wb.z + xb.w*wb.w;
    #pragma unroll
    for (int m = 1; m < 64; m <<= 1) d += __shfl_xor(d, m);
    if (lane == 0) {
        float z = d + bias[0];
        float e = vexp2(-z * 1.442695040888963f);
        sp[row] = 1.0f / (1.0f + e);
    }
}

// ---------------- kernel 2: scan — TWO rows per block, phase-shifted pipeline ----------
// Row A's LDS exchange round-trips while row B's elementwise runs, and vice versa.
// Per-row math is the R2-proven form. Output store is lagged one step (row s-1 stored
// during step s's shadow). 2 barriers per iteration; each iteration = 1 step per row.

// elementwise step: an = (c1*raw + c0*shift(raw) + 1e-6)^sq ; partials p1,p2; bnd
#define ELEM(raw, spv, carry, u, inv, an, P1, P2, BND) do {                          \
    float sq_ = 1.7f - fabsf((u) - 0.5f);                                            \
    float c1_ = (1.0f - (u)) * (inv);                                                \
    float c0_ = (u) * (inv);                                                         \
    float prev_ = wave_shr1(raw[3]);                                                 \
    float sh_ = (lane == 0) ? (carry) : prev_;                                       \
    an[0] = vexp2(sq_ * vlog2(fmaf(c1_, raw[0], fmaf(c0_, sh_,    1e-6f))));         \
    an[1] = vexp2(sq_ * vlog2(fmaf(c1_, raw[1], fmaf(c0_, raw[0], 1e-6f))));         \
    an[2] = vexp2(sq_ * vlog2(fmaf(c1_, raw[2], fmaf(c0_, raw[1], 1e-6f))));         \
    an[3] = vexp2(sq_ * vlog2(fmaf(c1_, raw[3], fmaf(c0_, raw[2], 1e-6f))));         \
    P1 = (an[0] + an[1]) + (an[2] + an[3]);                                          \
    P2 = fmaf(an[0], spv[0], an[1]*spv[1]) + fmaf(an[2], spv[2], an[3]*spv[3]);      \
    P1 = reduce63(P1);                                                               \
    P2 = reduce63(P2);                                                               \
    BND = an[3];                                                                     \
} while (0)

__global__ __launch_bounds__(256) void scan_kernel(const float* __restrict__ sp,
                                                   float* __restrict__ alphas)
{
    const int bA   = blockIdx.x * 2;
    const int bB   = bA + 1;
    const int tx   = threadIdx.x;
    const int lane = tx & 63;
    const int wid  = tx >> 6;

    __shared__ __align__(16) float r1A[2][4], r2A[2][4], rbA[2][4];
    __shared__ __align__(16) float r1B[2][4], r2B[2][4], rbB[2][4];

    float spA[4], spB[4], rawA[4], rawB[4];
    {
        float4 v = *reinterpret_cast<const float4*>(sp + (size_t)bA * NT + tx * 4);
        spA[0]=v.x; spA[1]=v.y; spA[2]=v.z; spA[3]=v.w;
        float4 w = *reinterpret_cast<const float4*>(sp + (size_t)bB * NT + tx * 4);
        spB[0]=w.x; spB[1]=w.y; spB[2]=w.z; spB[3]=w.w;
    }
    #pragma unroll
    for (int j = 0; j < 4; ++j) { rawA[j] = 1e-7f; rawB[j] = 1e-7f; }
    if (tx == 0) { rawA[0] = 1.0f; rawB[0] = 1.0f; }
    float carryA = (wid == 0) ? 0.0f : 1e-7f;
    float carryB = carryA;

    // prologue: initial u for both rows (alpha0 raw, inv=1 — matches reference)
    {
        float qA = fmaf(rawA[0], spA[0], fmaf(rawA[1], spA[1], fmaf(rawA[2], spA[2], rawA[3]*spA[3])));
        float qB = fmaf(rawB[0], spB[0], fmaf(rawB[1], spB[1], fmaf(rawB[2], spB[2], rawB[3]*spB[3])));
        qA = reduce63(qA);
        qB = reduce63(qB);
        if (lane == 63) { r2A[1][wid] = qA; r2B[1][wid] = qB; }
    }
    lds_barrier();
    float uA, uB;
    {
        float4 vA = *reinterpret_cast<const float4*>(r2A[1]);
        float4 vB = *reinterpret_cast<const float4*>(r2B[1]);
        uA = (vA.x + vA.y) + (vA.z + vA.w);
        uB = (vB.x + vB.y) + (vB.z + vB.w);
    }
    float invA = 1.0f, invB = 1.0f;

    // A's step-0 elementwise (fills the pipeline)
    float anA[4], anB[4];
    float p1A, p2A, bndA, p1B, p2B, bndB;
    ELEM(rawA, spA, carryA, uA, invA, anA, p1A, p2A, bndA);

    float* outA = alphas + (size_t)bA * NS * NT + tx * 4;
    float* outB = alphas + (size_t)bB * NS * NT + tx * 4;

    for (int s = 0; s < NS; ++s) {
        const int p = s & 1;

        // publish A's step-s partials
        if (lane == 63) { r1A[p][wid] = p1A; r2A[p][wid] = p2A; rbA[p][wid] = bndA; }

        // B's step-s elementwise (independent — hides A's exchange round trip)
        ELEM(rawB, spB, carryB, uB, invB, anB, p1B, p2B, bndB);

        // lagged store: A row s-1 (rawA/invA are step s-1's committed state)
        if (s) {
            float4 o;
            o.x = rawA[0]*invA; o.y = rawA[1]*invA; o.z = rawA[2]*invA; o.w = rawA[3]*invA;
            *reinterpret_cast<float4*>(outA) = o;
            outA += NT;
        }
        lds_barrier();

        // commit A step s
        {
            float4 v1 = *reinterpret_cast<const float4*>(r1A[p]);
            float4 v2 = *reinterpret_cast<const float4*>(r2A[p]);
            float bc  = rbA[p][(wid == 0) ? 0 : (wid - 1)];
            carryA = (wid == 0) ? 0.0f : bc;
            float t1 = (v1.x + v1.y) + (v1.z + v1.w);
            float t2 = (v2.x + v2.y) + (v2.z + v2.w);
            invA = vrcp(t1);
            uA   = t2 * invA;
        }
        #pragma unroll
        for (int j = 0; j < 4; ++j) rawA[j] = anA[j];

        // publish B's step-s partials
        if (lane == 63) { r1B[p][wid] = p1B; r2B[p][wid] = p2B; rbB[p][wid] = bndB; }

        // A's step-(s+1) elementwise (hides B's exchange round trip)
        ELEM(rawA, spA, carryA, uA, invA, anA, p1A, p2A, bndA);

        // lagged store: B row s-1
        if (s) {
            float4 o;
            o.x = rawB[0]*invB; o.y = rawB[1]*invB; o.z = rawB[2]*invB; o.w = rawB[3]*invB;
            *reinterpret_cast<float4*>(outB) = o;
            outB += NT;
        }
        lds_barrier();

        // commit B step s
        {
            float4 v1 = *reinterpret_cast<const float4*>(r1B[p]);
            float4 v2 = *reinterpret_cast<const float4*>(r2B[p]);
            float bc  = rbB[p][(wid == 0) ? 0 : (wid - 1)];
            carryB = (wid == 0) ? 0.0f : bc;
            float t1 = (v1.x + v1.y) + (v1.z + v1.w);
            float t2 = (v2.x + v2.y) + (v2.z + v2.w);
            invB = vrcp(t1);
            uB   = t2 * invB;
        }
        #pragma unroll
        for (int j = 0; j < 4; ++j) rawB[j] = anB[j];
    }

    // final rows (NS-1) for both
    {
        float4 o;
        o.x = rawA[0]*invA; o.y = rawA[1]*invA; o.z = rawA[2]*invA; o.w = rawA[3]*invA;
        *reinterpret_cast<float4*>(outA) = o;
        o.x = rawB[0]*invB; o.y = rawB[1]*invB; o.z = rawB[2]*invB; o.w = rawB[3]*invB;
        *reinterpret_cast<float4*>(outB) = o;
    }
}

// ---------------- kernel 3: contexts[b] = alphas[b] (SxT) @ x[b] (TxD), bf16 MFMA ------
// 256x256 tile, 512 threads = 8 waves (2 x 4), each wave owns 128x64
typedef __bf16 bf16x8 __attribute__((ext_vector_type(8)));
typedef float  f32x4  __attribute__((ext_vector_type(4)));

#define BM 256
#define BN 256
#define BK 32
#define LDP 40   // padded leading dim (bf16 elems)

__global__ __launch_bounds__(512, 2) void gemm_kernel(const float* __restrict__ alphas,
                                                      const float* __restrict__ x,
                                                      float* __restrict__ contexts)
{
    __shared__ __align__(16) __bf16 As[BM * LDP];   // As[row][k]   20 KB
    __shared__ __align__(16) __bf16 Xs[BN * LDP];   // Xs[n][k]     20 KB (transposed)

    const int b  = blockIdx.z;
    const int s0 = blockIdx.y * BM;
    const int n0 = blockIdx.x * BN;
    const int tx = threadIdx.x;
    const int lane = tx & 63;
    const int wid  = tx >> 6;
    const int wm = wid >> 2;          // 0..1  (128-row slab)
    const int wn = wid & 3;           // 0..3  (64-col slab)
    const int lr = lane & 15;
    const int lk = (lane >> 4) * 8;

    f32x4 acc[8][4];
    #pragma unroll
    for (int i = 0; i < 8; ++i)
        #pragma unroll
        for (int j = 0; j < 4; ++j) acc[i][j] = (f32x4){0.f, 0.f, 0.f, 0.f};

    const int arow = tx >> 1;
    const int akb  = (tx & 1) * 16;
    const int xk0 = tx >> 6;          // 0..7
    const int xn4 = (tx & 63) * 4;    // 0..252

    const float* ap = alphas + ((size_t)b * NS + s0 + arow) * NT + akb;
    const float* xp = x + ((size_t)b * NT + xk0) * ND + n0 + xn4;

    float4 va0 = reinterpret_cast<const float4*>(ap)[0];
    float4 va1 = reinterpret_cast<const float4*>(ap)[1];
    float4 va2 = reinterpret_cast<const float4*>(ap)[2];
    float4 va3 = reinterpret_cast<const float4*>(ap)[3];
    float4 vx0 = *reinterpret_cast<const float4*>(xp + 0 * 8 * ND);
    float4 vx1 = *reinterpret_cast<const float4*>(xp + 1 * 8 * ND);
    float4 vx2 = *reinterpret_cast<const float4*>(xp + 2 * 8 * ND);
    float4 vx3 = *reinterpret_cast<const float4*>(xp + 3 * 8 * ND);
    ap += BK;
    xp += (size_t)BK * ND;

    for (int k0 = 0; k0 < NT; k0 += BK) {
        {
            bf16x8 w0, w1;
            w0[0]=(__bf16)va0.x; w0[1]=(__bf16)va0.y; w0[2]=(__bf16)va0.z; w0[3]=(__bf16)va0.w;
            w0[4]=(__bf16)va1.x; w0[5]=(__bf16)va1.y; w0[6]=(__bf16)va1.z; w0[7]=(__bf16)va1.w;
            w1[0]=(__bf16)va2.x; w1[1]=(__bf16)va2.y; w1[2]=(__bf16)va2.z; w1[3]=(__bf16)va2.w;
            w1[4]=(__bf16)va3.x; w1[5]=(__bf16)va3.y; w1[6]=(__bf16)va3.z; w1[7]=(__bf16)va3.w;
            *reinterpret_cast<bf16x8*>(&As[arow * LDP + akb])     = w0;
            *reinterpret_cast<bf16x8*>(&As[arow * LDP + akb + 8]) = w1;
            Xs[(xn4+0)*LDP + xk0]      = (__bf16)vx0.x;
            Xs[(xn4+1)*LDP + xk0]      = (__bf16)vx0.y;
            Xs[(xn4+2)*LDP + xk0]      = (__bf16)vx0.z;
            Xs[(xn4+3)*LDP + xk0]      = (__bf16)vx0.w;
            Xs[(xn4+0)*LDP + xk0 + 8]  = (__bf16)vx1.x;
            Xs[(xn4+1)*LDP + xk0 + 8]  = (__bf16)vx1.y;
            Xs[(xn4+2)*LDP + xk0 + 8]  = (__bf16)vx1.z;
            Xs[(xn4+3)*LDP + xk0 + 8]  = (__bf16)vx1.w;
            Xs[(xn4+0)*LDP + xk0 + 16] = (__bf16)vx2.x;
            Xs[(xn4+1)*LDP + xk0 + 16] = (__bf16)vx2.y;
            Xs[(xn4+2)*LDP + xk0 + 16] = (__bf16)vx2.z;
            Xs[(xn4+3)*LDP + xk0 + 16] = (__bf16)vx2.w;
            Xs[(xn4+0)*LDP + xk0 + 24] = (__bf16)vx3.x;
            Xs[(xn4+1)*LDP + xk0 + 24] = (__bf16)vx3.y;
            Xs[(xn4+2)*LDP + xk0 + 24] = (__bf16)vx3.z;
            Xs[(xn4+3)*LDP + xk0 + 24] = (__bf16)vx3.w;
        }
        if (k0 + BK < NT) {
            va0 = reinterpret_cast<const float4*>(ap)[0];
            va1 = reinterpret_cast<const float4*>(ap)[1];
            va2 = reinterpret_cast<const float4*>(ap)[2];
            va3 = reinterpret_cast<const float4*>(ap)[3];
            vx0 = *reinterpret_cast<const float4*>(xp + 0 * 8 * ND);
            vx1 = *reinterpret_cast<const float4*>(xp + 1 * 8 * ND);
            vx2 = *reinterpret_cast<const float4*>(xp + 2 * 8 * ND);
            vx3 = *reinterpret_cast<const float4*>(xp + 3 * 8 * ND);
            ap += BK;
            xp += (size_t)BK * ND;
        }
        lds_barrier();   // lgkm-only — prefetch global loads stay in flight

        bf16x8 av[8], bv[4];
        #pragma unroll
        for (int j = 0; j < 4; ++j)
            bv[j] = *reinterpret_cast<const bf16x8*>(&Xs[(wn*64 + j*16 + lr) * LDP + lk]);
        #pragma unroll
        for (int i = 0; i < 8; ++i)
            av[i] = *reinterpret_cast<const bf16x8*>(&As[(wm*128 + i*16 + lr) * LDP + lk]);
        #pragma unroll
        for (int i = 0; i < 8; ++i)
            #pragma unroll
            for (int j = 0; j < 4; ++j)
                acc[i][j] = __builtin_amdgcn_mfma_f32_16x16x32_bf16(av[i], bv[j], acc[i][j], 0, 0, 0);
        lds_barrier();
    }

    const int ccol = lr;
    const int crow = (lane >> 4) * 4;
    #pragma unroll
    for (int i = 0; i < 8; ++i) {
        #pragma unroll
        for (int j = 0; j < 4; ++j) {
            int col = n0 + wn*64 + j*16 + ccol;
            int rw  = s0 + wm*128 + i*16 + crow;
            #pragma unroll
            for (int r = 0; r < 4; ++r)
                contexts[((size_t)b * NS + rw + r) * ND + col] = acc[i][j][r];
        }
    }
}

extern "C" void kernel_launch(void* const* d_in, const int* in_sizes, int n_in,
                              void* d_out, int out_size, void* d_ws, size_t ws_size,
                              hipStream_t stream) {
    const float* x    = (const float*)d_in[0];
    const float* W    = (const float*)d_in[1];
    const float* bias = (const float*)d_in[2];
    float* contexts = (float*)d_out;
    float* alphas   = (float*)d_out + CTX_ELEMS;
    float* sp       = (float*)d_out + SP_SCRATCH_OFF;

    sp_kernel<<<dim3(NB * NT / 4), dim3(256), 0, stream>>>(x, W, bias, sp);
    scan_kernel<<<dim3(NB / 2), dim3(256), 0, stream>>>(sp, alphas);
    gemm_kernel<<<dim3(ND / BN, NS / BM, NB), dim3(512), 0, stream>>>(alphas, x, contexts);
}

// Round 8
// 545.372 us; speedup vs baseline: 1.4215x; 1.4215x over previous
//
#include <hip/hip_runtime.h>
#include <hip/hip_bf16.h>

#define NB 32
#define NT 1024
#define ND 512
#define NS 1024

#define CTX_ELEMS (32u * 1024u * 512u)          // 16777216
#define SP_SCRATCH_OFF (CTX_ELEMS - 32u*1024u)  // stash sp in contexts tail (overwritten later)

__device__ __forceinline__ float vlog2(float x) {
    float r; asm("v_log_f32 %0, %1" : "=v"(r) : "v"(x)); return r;
}
__device__ __forceinline__ float vexp2(float x) {
    float r; asm("v_exp_f32 %0, %1" : "=v"(r) : "v"(x)); return r;
}
__device__ __forceinline__ float vrcp(float x) {
    float r; asm("v_rcp_f32 %0, %1" : "=v"(r) : "v"(x)); return r;
}

template<int ctrl, int rm, int bm, bool bc>
__device__ __forceinline__ float dppadd(float x) {
    int y = __builtin_amdgcn_update_dpp(0, __float_as_int(x), ctrl, rm, bm, bc);
    return x + __int_as_float(y);
}
// full-wave sum; valid result lands in lane 63
__device__ __forceinline__ float reduce63(float x) {
    x = dppadd<0x111, 0xf, 0xf, true >(x);   // row_shr:1
    x = dppadd<0x112, 0xf, 0xf, true >(x);   // row_shr:2
    x = dppadd<0x114, 0xf, 0xf, true >(x);   // row_shr:4
    x = dppadd<0x118, 0xf, 0xf, true >(x);   // row_shr:8
    x = dppadd<0x142, 0xa, 0xf, false>(x);   // row_bcast:15
    x = dppadd<0x143, 0xc, 0xf, false>(x);   // row_bcast:31
    return x;
}
// lane L receives x from lane L-1 (lane 0 gets 0)
__device__ __forceinline__ float wave_shr1(float x) {
    int y = __builtin_amdgcn_update_dpp(0, __float_as_int(x), 0x138, 0xf, 0xf, true);
    return __int_as_float(y);
}
// uniform broadcast of lane 63's value
__device__ __forceinline__ float rdlane63(float x) {
    return __int_as_float(__builtin_amdgcn_readlane(__float_as_int(x), 63));
}

// barrier that waits ONLY on LDS ops — global stores stay in flight
__device__ __forceinline__ void lds_barrier() {
    asm volatile("s_waitcnt lgkmcnt(0)" ::: "memory");
    __builtin_amdgcn_s_barrier();
    asm volatile("" ::: "memory");
}

// ---------------- kernel 1: sp[b][t] = sigmoid(dot(x[b,t,:], W) + bias) ----------------
__global__ __launch_bounds__(256) void sp_kernel(const float* __restrict__ x,
                                                 const float* __restrict__ W,
                                                 const float* __restrict__ bias,
                                                 float* __restrict__ sp)
{
    const int lane = threadIdx.x & 63;
    const int wid  = threadIdx.x >> 6;
    const int row  = blockIdx.x * 4 + wid;          // b*NT + t
    const float4* xr = reinterpret_cast<const float4*>(x + (size_t)row * ND) + lane * 2;
    const float4* wr = reinterpret_cast<const float4*>(W) + lane * 2;
    float4 xa = xr[0], xb = xr[1];
    float4 wa = wr[0], wb = wr[1];
    float d = xa.x*wa.x + xa.y*wa.y + xa.z*wa.z + xa.w*wa.w
            + xb.x*wb.x + xb.y*wb.y + xb.z*wb.z + xb.w*wb.w;
    #pragma unroll
    for (int m = 1; m < 64; m <<= 1) d += __shfl_xor(d, m);
    if (lane == 0) {
        float z = d + bias[0];
        float e = vexp2(-z * 1.442695040888963f);
        sp[row] = 1.0f / (1.0f + e);
    }
}

// ---------------- kernel 2: SINGLE-WAVE scan, 16 elems/lane, zero barriers -------------
// lane owns t = j*256 + lane*4 + c  (j=0..3, c=0..3) -> coalesced float4 loads/stores.
// Cross-lane: wave_shr1 (DPP) for shifts, reduce63+readlane for the two sums.

#define EROW(RAW, AN, j, SH0)                                                          \
    AN[j][0] = vexp2(sq * vlog2(fmaf(c1, RAW[j][0], fmaf(c0, SH0,       1e-6f))));     \
    AN[j][1] = vexp2(sq * vlog2(fmaf(c1, RAW[j][1], fmaf(c0, RAW[j][0], 1e-6f))));     \
    AN[j][2] = vexp2(sq * vlog2(fmaf(c1, RAW[j][2], fmaf(c0, RAW[j][1], 1e-6f))));     \
    AN[j][3] = vexp2(sq * vlog2(fmaf(c1, RAW[j][3], fmaf(c0, RAW[j][2], 1e-6f))));

#define STEP(RAW, AN)                                                                  \
    do {                                                                               \
        const float sq = 1.7f - fabsf(u - 0.5f);                                       \
        const float c1 = (1.0f - u) * inv;                                             \
        const float c0 = u * inv;                                                      \
        float bndA = rdlane63(RAW[0][3]);                                              \
        float bndB = rdlane63(RAW[1][3]);                                              \
        float bndC = rdlane63(RAW[2][3]);                                              \
        float pr0 = wave_shr1(RAW[0][3]);                                              \
        float pr1 = wave_shr1(RAW[1][3]);                                              \
        float pr2 = wave_shr1(RAW[2][3]);                                              \
        float pr3 = wave_shr1(RAW[3][3]);                                              \
        float sh0 = (lane == 0) ? 0.0f : pr0;                                          \
        float sh1 = (lane == 0) ? bndA : pr1;                                          \
        float sh2 = (lane == 0) ? bndB : pr2;                                          \
        float sh3 = (lane == 0) ? bndC : pr3;                                          \
        EROW(RAW, AN, 0, sh0)                                                          \
        EROW(RAW, AN, 1, sh1)                                                          \
        EROW(RAW, AN, 2, sh2)                                                          \
        EROW(RAW, AN, 3, sh3)                                                          \
        float s0 = (AN[0][0] + AN[0][1]) + (AN[0][2] + AN[0][3]);                      \
        float s1 = (AN[1][0] + AN[1][1]) + (AN[1][2] + AN[1][3]);                      \
        float s2 = (AN[2][0] + AN[2][1]) + (AN[2][2] + AN[2][3]);                      \
        float s3 = (AN[3][0] + AN[3][1]) + (AN[3][2] + AN[3][3]);                      \
        float q0 = fmaf(AN[0][0], spv[0][0], AN[0][1]*spv[0][1])                       \
                 + fmaf(AN[0][2], spv[0][2], AN[0][3]*spv[0][3]);                      \
        float q1 = fmaf(AN[1][0], spv[1][0], AN[1][1]*spv[1][1])                       \
                 + fmaf(AN[1][2], spv[1][2], AN[1][3]*spv[1][3]);                      \
        float q2 = fmaf(AN[2][0], spv[2][0], AN[2][1]*spv[2][1])                       \
                 + fmaf(AN[2][2], spv[2][2], AN[2][3]*spv[2][3]);                      \
        float q3 = fmaf(AN[3][0], spv[3][0], AN[3][1]*spv[3][1])                       \
                 + fmaf(AN[3][2], spv[3][2], AN[3][3]*spv[3][3]);                      \
        float p1 = (s0 + s1) + (s2 + s3);                                              \
        float p2 = (q0 + q1) + (q2 + q3);                                              \
        p1 = reduce63(p1);                                                             \
        p2 = reduce63(p2);                                                             \
        float t1 = rdlane63(p1);                                                       \
        float t2 = rdlane63(p2);                                                       \
        inv = vrcp(t1);                                                                \
        u   = t2 * inv;                                                                \
        float4 o;                                                                      \
        o.x = AN[0][0]*inv; o.y = AN[0][1]*inv; o.z = AN[0][2]*inv; o.w = AN[0][3]*inv;\
        *reinterpret_cast<float4*>(outp + 0*256) = o;                                  \
        o.x = AN[1][0]*inv; o.y = AN[1][1]*inv; o.z = AN[1][2]*inv; o.w = AN[1][3]*inv;\
        *reinterpret_cast<float4*>(outp + 1*256) = o;                                  \
        o.x = AN[2][0]*inv; o.y = AN[2][1]*inv; o.z = AN[2][2]*inv; o.w = AN[2][3]*inv;\
        *reinterpret_cast<float4*>(outp + 2*256) = o;                                  \
        o.x = AN[3][0]*inv; o.y = AN[3][1]*inv; o.z = AN[3][2]*inv; o.w = AN[3][3]*inv;\
        *reinterpret_cast<float4*>(outp + 3*256) = o;                                  \
        outp += NT;                                                                    \
    } while (0)

__global__ __launch_bounds__(64) void scan_kernel(const float* __restrict__ sp,
                                                  float* __restrict__ alphas)
{
    const int b    = blockIdx.x;
    const int lane = threadIdx.x;          // 0..63

    float spv[4][4], raw[4][4], an[4][4];
    #pragma unroll
    for (int j = 0; j < 4; ++j) {
        float4 v = *reinterpret_cast<const float4*>(sp + (size_t)b * NT + j * 256 + lane * 4);
        spv[j][0] = v.x; spv[j][1] = v.y; spv[j][2] = v.z; spv[j][3] = v.w;
    }
    #pragma unroll
    for (int j = 0; j < 4; ++j)
        #pragma unroll
        for (int c = 0; c < 4; ++c) raw[j][c] = 1e-7f;
    if (lane == 0) raw[0][0] = 1.0f;

    // initial u = sum(alpha0 * sp) with raw (unnormalized) alpha0 — matches reference
    float u;
    {
        float q0 = fmaf(raw[0][0], spv[0][0], raw[0][1]*spv[0][1])
                 + fmaf(raw[0][2], spv[0][2], raw[0][3]*spv[0][3]);
        float q1 = fmaf(raw[1][0], spv[1][0], raw[1][1]*spv[1][1])
                 + fmaf(raw[1][2], spv[1][2], raw[1][3]*spv[1][3]);
        float q2 = fmaf(raw[2][0], spv[2][0], raw[2][1]*spv[2][1])
                 + fmaf(raw[2][2], spv[2][2], raw[2][3]*spv[2][3]);
        float q3 = fmaf(raw[3][0], spv[3][0], raw[3][1]*spv[3][1])
                 + fmaf(raw[3][2], spv[3][2], raw[3][3]*spv[3][3]);
        float p2 = (q0 + q1) + (q2 + q3);
        p2 = reduce63(p2);
        u = rdlane63(p2);
    }
    float inv = 1.0f;

    float* outp = alphas + (size_t)b * NS * NT + lane * 4;

    for (int s = 0; s < NS; s += 2) {
        STEP(raw, an);      // writes row s,   state in an
        STEP(an, raw);      // writes row s+1, state back in raw
    }
}

// ---------------- kernel 3: contexts[b] = alphas[b] (SxT) @ x[b] (TxD), bf16 MFMA ------
// 256x256 tile, 512 threads = 8 waves (2 x 4), each wave owns 128x64
typedef __bf16 bf16x8 __attribute__((ext_vector_type(8)));
typedef float  f32x4  __attribute__((ext_vector_type(4)));

#define BM 256
#define BN 256
#define BK 32
#define LDP 40   // padded leading dim (bf16 elems)

__global__ __launch_bounds__(512, 2) void gemm_kernel(const float* __restrict__ alphas,
                                                      const float* __restrict__ x,
                                                      float* __restrict__ contexts)
{
    __shared__ __align__(16) __bf16 As[BM * LDP];   // As[row][k]   20 KB
    __shared__ __align__(16) __bf16 Xs[BN * LDP];   // Xs[n][k]     20 KB (transposed)

    const int b  = blockIdx.z;
    const int s0 = blockIdx.y * BM;
    const int n0 = blockIdx.x * BN;
    const int tx = threadIdx.x;
    const int lane = tx & 63;
    const int wid  = tx >> 6;
    const int wm = wid >> 2;          // 0..1  (128-row slab)
    const int wn = wid & 3;           // 0..3  (64-col slab)
    const int lr = lane & 15;
    const int lk = (lane >> 4) * 8;

    f32x4 acc[8][4];
    #pragma unroll
    for (int i = 0; i < 8; ++i)
        #pragma unroll
        for (int j = 0; j < 4; ++j) acc[i][j] = (f32x4){0.f, 0.f, 0.f, 0.f};

    const int arow = tx >> 1;
    const int akb  = (tx & 1) * 16;
    const int xk0 = tx >> 6;          // 0..7
    const int xn4 = (tx & 63) * 4;    // 0..252

    const float* ap = alphas + ((size_t)b * NS + s0 + arow) * NT + akb;
    const float* xp = x + ((size_t)b * NT + xk0) * ND + n0 + xn4;

    float4 va0 = reinterpret_cast<const float4*>(ap)[0];
    float4 va1 = reinterpret_cast<const float4*>(ap)[1];
    float4 va2 = reinterpret_cast<const float4*>(ap)[2];
    float4 va3 = reinterpret_cast<const float4*>(ap)[3];
    float4 vx0 = *reinterpret_cast<const float4*>(xp + 0 * 8 * ND);
    float4 vx1 = *reinterpret_cast<const float4*>(xp + 1 * 8 * ND);
    float4 vx2 = *reinterpret_cast<const float4*>(xp + 2 * 8 * ND);
    float4 vx3 = *reinterpret_cast<const float4*>(xp + 3 * 8 * ND);
    ap += BK;
    xp += (size_t)BK * ND;

    for (int k0 = 0; k0 < NT; k0 += BK) {
        {
            bf16x8 w0, w1;
            w0[0]=(__bf16)va0.x; w0[1]=(__bf16)va0.y; w0[2]=(__bf16)va0.z; w0[3]=(__bf16)va0.w;
            w0[4]=(__bf16)va1.x; w0[5]=(__bf16)va1.y; w0[6]=(__bf16)va1.z; w0[7]=(__bf16)va1.w;
            w1[0]=(__bf16)va2.x; w1[1]=(__bf16)va2.y; w1[2]=(__bf16)va2.z; w1[3]=(__bf16)va2.w;
            w1[4]=(__bf16)va3.x; w1[5]=(__bf16)va3.y; w1[6]=(__bf16)va3.z; w1[7]=(__bf16)va3.w;
            *reinterpret_cast<bf16x8*>(&As[arow * LDP + akb])     = w0;
            *reinterpret_cast<bf16x8*>(&As[arow * LDP + akb + 8]) = w1;
            Xs[(xn4+0)*LDP + xk0]      = (__bf16)vx0.x;
            Xs[(xn4+1)*LDP + xk0]      = (__bf16)vx0.y;
            Xs[(xn4+2)*LDP + xk0]      = (__bf16)vx0.z;
            Xs[(xn4+3)*LDP + xk0]      = (__bf16)vx0.w;
            Xs[(xn4+0)*LDP + xk0 + 8]  = (__bf16)vx1.x;
            Xs[(xn4+1)*LDP + xk0 + 8]  = (__bf16)vx1.y;
            Xs[(xn4+2)*LDP + xk0 + 8]  = (__bf16)vx1.z;
            Xs[(xn4+3)*LDP + xk0 + 8]  = (__bf16)vx1.w;
            Xs[(xn4+0)*LDP + xk0 + 16] = (__bf16)vx2.x;
            Xs[(xn4+1)*LDP + xk0 + 16] = (__bf16)vx2.y;
            Xs[(xn4+2)*LDP + xk0 + 16] = (__bf16)vx2.z;
            Xs[(xn4+3)*LDP + xk0 + 16] = (__bf16)vx2.w;
            Xs[(xn4+0)*LDP + xk0 + 24] = (__bf16)vx3.x;
            Xs[(xn4+1)*LDP + xk0 + 24] = (__bf16)vx3.y;
            Xs[(xn4+2)*LDP + xk0 + 24] = (__bf16)vx3.z;
            Xs[(xn4+3)*LDP + xk0 + 24] = (__bf16)vx3.w;
        }
        if (k0 + BK < NT) {
            va0 = reinterpret_cast<const float4*>(ap)[0];
            va1 = reinterpret_cast<const float4*>(ap)[1];
            va2 = reinterpret_cast<const float4*>(ap)[2];
            va3 = reinterpret_cast<const float4*>(ap)[3];
            vx0 = *reinterpret_cast<const float4*>(xp + 0 * 8 * ND);
            vx1 = *reinterpret_cast<const float4*>(xp + 1 * 8 * ND);
            vx2 = *reinterpret_cast<const float4*>(xp + 2 * 8 * ND);
            vx3 = *reinterpret_cast<const float4*>(xp + 3 * 8 * ND);
            ap += BK;
            xp += (size_t)BK * ND;
        }
        lds_barrier();   // lgkm-only — prefetch global loads stay in flight

        bf16x8 av[8], bv[4];
        #pragma unroll
        for (int j = 0; j < 4; ++j)
            bv[j] = *reinterpret_cast<const bf16x8*>(&Xs[(wn*64 + j*16 + lr) * LDP + lk]);
        #pragma unroll
        for (int i = 0; i < 8; ++i)
            av[i] = *reinterpret_cast<const bf16x8*>(&As[(wm*128 + i*16 + lr) * LDP + lk]);
        #pragma unroll
        for (int i = 0; i < 8; ++i)
            #pragma unroll
            for (int j = 0; j < 4; ++j)
                acc[i][j] = __builtin_amdgcn_mfma_f32_16x16x32_bf16(av[i], bv[j], acc[i][j], 0, 0, 0);
        lds_barrier();
    }

    const int ccol = lr;
    const int crow = (lane >> 4) * 4;
    #pragma unroll
    for (int i = 0; i < 8; ++i) {
        #pragma unroll
        for (int j = 0; j < 4; ++j) {
            int col = n0 + wn*64 + j*16 + ccol;
            int rw  = s0 + wm*128 + i*16 + crow;
            #pragma unroll
            for (int r = 0; r < 4; ++r)
                contexts[((size_t)b * NS + rw + r) * ND + col] = acc[i][j][r];
        }
    }
}

extern "C" void kernel_launch(void* const* d_in, const int* in_sizes, int n_in,
                              void* d_out, int out_size, void* d_ws, size_t ws_size,
                              hipStream_t stream) {
    const float* x    = (const float*)d_in[0];
    const float* W    = (const float*)d_in[1];
    const float* bias = (const float*)d_in[2];
    float* contexts = (float*)d_out;
    float* alphas   = (float*)d_out + CTX_ELEMS;
    float* sp       = (float*)d_out + SP_SCRATCH_OFF;

    sp_kernel<<<dim3(NB * NT / 4), dim3(256), 0, stream>>>(x, W, bias, sp);
    scan_kernel<<<dim3(NB), dim3(64), 0, stream>>>(sp, alphas);
    gemm_kernel<<<dim3(ND / BN, NS / BM, NB), dim3(512), 0, stream>>>(alphas, x, contexts);
}

// Round 9
// 477.585 us; speedup vs baseline: 1.6232x; 1.1419x over previous
//
#include <hip/hip_runtime.h>
#include <hip/hip_bf16.h>

#define NB 32
#define NT 1024
#define ND 512
#define NS 1024

#define CTX_ELEMS (32u * 1024u * 512u)          // 16777216
#define SP_SCRATCH_OFF (CTX_ELEMS - 32u*1024u)  // stash sp in contexts tail (overwritten later)

__device__ __forceinline__ float vlog2(float x) {
    float r; asm("v_log_f32 %0, %1" : "=v"(r) : "v"(x)); return r;
}
__device__ __forceinline__ float vexp2(float x) {
    float r; asm("v_exp_f32 %0, %1" : "=v"(r) : "v"(x)); return r;
}
__device__ __forceinline__ float vrcp(float x) {
    float r; asm("v_rcp_f32 %0, %1" : "=v"(r) : "v"(x)); return r;
}

template<int ctrl, int rm, int bm, bool bc>
__device__ __forceinline__ float dppadd(float x) {
    int y = __builtin_amdgcn_update_dpp(0, __float_as_int(x), ctrl, rm, bm, bc);
    return x + __int_as_float(y);
}
// full-wave sum; valid result lands in lane 63
__device__ __forceinline__ float reduce63(float x) {
    x = dppadd<0x111, 0xf, 0xf, true >(x);   // row_shr:1
    x = dppadd<0x112, 0xf, 0xf, true >(x);   // row_shr:2
    x = dppadd<0x114, 0xf, 0xf, true >(x);   // row_shr:4
    x = dppadd<0x118, 0xf, 0xf, true >(x);   // row_shr:8
    x = dppadd<0x142, 0xa, 0xf, false>(x);   // row_bcast:15
    x = dppadd<0x143, 0xc, 0xf, false>(x);   // row_bcast:31
    return x;
}
// lane L receives x from lane L-1 (lane 0 gets 0)
__device__ __forceinline__ float wave_shr1(float x) {
    int y = __builtin_amdgcn_update_dpp(0, __float_as_int(x), 0x138, 0xf, 0xf, true);
    return __int_as_float(y);
}

// barrier that waits ONLY on LDS ops — global stores stay in flight
__device__ __forceinline__ void lds_barrier() {
    asm volatile("s_waitcnt lgkmcnt(0)" ::: "memory");
    __builtin_amdgcn_s_barrier();
    asm volatile("" ::: "memory");
}

// ---------------- kernel 1: sp[b][t] = sigmoid(dot(x[b,t,:], W) + bias) ----------------
__global__ __launch_bounds__(256) void sp_kernel(const float* __restrict__ x,
                                                 const float* __restrict__ W,
                                                 const float* __restrict__ bias,
                                                 float* __restrict__ sp)
{
    const int lane = threadIdx.x & 63;
    const int wid  = threadIdx.x >> 6;
    const int row  = blockIdx.x * 4 + wid;          // b*NT + t
    const float4* xr = reinterpret_cast<const float4*>(x + (size_t)row * ND) + lane * 2;
    const float4* wr = reinterpret_cast<const float4*>(W) + lane * 2;
    float4 xa = xr[0], xb = xr[1];
    float4 wa = wr[0], wb = wr[1];
    float d = xa.x*wa.x + xa.y*wa.y + xa.z*wa.z + xa.w*wa.w
            + xb.x*wb.x + xb.y*wb.y + xb.z*wb.z + xb.w*wb.w;
    #pragma unroll
    for (int m = 1; m < 64; m <<= 1) d += __shfl_xor(d, m);
    if (lane == 0) {
        float z = d + bias[0];
        float e = vexp2(-z * 1.442695040888963f);
        sp[row] = 1.0f / (1.0f + e);
    }
}

// ---------------- kernel 2: sequential scan, 8 waves per batch row ------
// R2-proven exchange structure; W=8 halves the dominant trans-issue term.
// thread tx owns t = tx*2, tx*2+1 ; wave w owns t = w*128 .. w*128+127
__global__ __launch_bounds__(512) void scan_kernel(const float* __restrict__ sp,
                                                   float* __restrict__ alphas)
{
    const int b    = blockIdx.x;
    const int tx   = threadIdx.x;          // 0..511
    const int lane = tx & 63;
    const int wid  = tx >> 6;              // 0..7

    __shared__ __align__(16) float r1[2][8];   // per-wave partial sum(a)
    __shared__ __align__(16) float r2[2][8];   // per-wave partial sum(a*sp)
    __shared__ __align__(16) float rb[2][8];   // per-wave boundary (unnorm a at t=w*128+127)

    float spv[2], raw[2];
    {
        float2 v = *reinterpret_cast<const float2*>(sp + (size_t)b * NT + tx * 2);
        spv[0] = v.x; spv[1] = v.y;
    }
    raw[0] = 1e-7f; raw[1] = 1e-7f;
    if (tx == 0) raw[0] = 1.0f;
    float carry = (wid == 0) ? 0.0f : 1e-7f;   // alpha at t = w*128 - 1

    // initial u = sum(alpha0 * sp), alpha0 raw (matches reference), inv = 1
    {
        float q = fmaf(raw[0], spv[0], raw[1] * spv[1]);
        q = reduce63(q);
        if (lane == 63) r2[1][wid] = q;
    }
    lds_barrier();
    float u;
    {
        float4 a = *reinterpret_cast<const float4*>(&r2[1][0]);
        float4 c = *reinterpret_cast<const float4*>(&r2[1][4]);
        u = ((a.x + a.y) + (a.z + a.w)) + ((c.x + c.y) + (c.z + c.w));
    }
    float inv = 1.0f;

    float* outp = alphas + (size_t)b * NS * NT + tx * 2;

    for (int s = 0; s < NS; ++s) {
        const int p = s & 1;
        const float sq = 1.7f - fabsf(u - 0.5f);
        const float c1 = (1.0f - u) * inv;
        const float c0 = u * inv;

        float prev = wave_shr1(raw[1]);
        float sh0  = (lane == 0) ? carry : prev;

        float an0 = vexp2(sq * vlog2(fmaf(c1, raw[0], fmaf(c0, sh0,    1e-6f))));
        float an1 = vexp2(sq * vlog2(fmaf(c1, raw[1], fmaf(c0, raw[0], 1e-6f))));

        float p1 = an0 + an1;
        float p2 = fmaf(an0, spv[0], an1 * spv[1]);
        p1 = reduce63(p1);
        p2 = reduce63(p2);
        if (lane == 63) { r1[p][wid] = p1; r2[p][wid] = p2; rb[p][wid] = an1; }
        lds_barrier();

        float4 a = *reinterpret_cast<const float4*>(&r1[p][0]);
        float4 bq = *reinterpret_cast<const float4*>(&r1[p][4]);
        float4 c = *reinterpret_cast<const float4*>(&r2[p][0]);
        float4 d = *reinterpret_cast<const float4*>(&r2[p][4]);
        float bc = rb[p][(wid == 0) ? 0 : (wid - 1)];
        carry = (wid == 0) ? 0.0f : bc;

        float t1 = ((a.x + a.y) + (a.z + a.w)) + ((bq.x + bq.y) + (bq.z + bq.w));
        float t2 = ((c.x + c.y) + (c.z + c.w)) + ((d.x + d.y) + (d.z + d.w));
        inv = vrcp(t1);
        u   = t2 * inv;

        float2 o;
        o.x = an0 * inv; o.y = an1 * inv;
        *reinterpret_cast<float2*>(outp + (size_t)s * NT) = o;

        raw[0] = an0; raw[1] = an1;
    }
}

// ---------------- kernel 3: contexts[b] = alphas[b] (SxT) @ x[b] (TxD), bf16 MFMA ------
// 256x256 tile, 512 threads = 8 waves (2 x 4), each wave owns 128x64.
// 1-D grid with XCD-pair swizzle: bids p and p+8 (same XCD under %8 round-robin)
// are the two n-tiles sharing one (b, s-block) A-panel -> A fetched once per L2.
typedef __bf16 bf16x8 __attribute__((ext_vector_type(8)));
typedef float  f32x4  __attribute__((ext_vector_type(4)));

#define BM 256
#define BN 256
#define BK 32
#define LDP 40   // padded leading dim (bf16 elems)

__global__ __launch_bounds__(512, 2) void gemm_kernel(const float* __restrict__ alphas,
                                                      const float* __restrict__ x,
                                                      float* __restrict__ contexts)
{
    __shared__ __align__(16) __bf16 As[BM * LDP];   // As[row][k]   20 KB
    __shared__ __align__(16) __bf16 Xs[BN * LDP];   // Xs[n][k]     20 KB (transposed)

    // XCD-pair decode
    const int bid  = blockIdx.x;
    const int low3 = bid & 7;
    const int slot = bid >> 3;            // 0..31
    const int nb   = slot & 1;
    const int pair = (slot >> 1) * 8 + low3;   // 0..127
    const int b    = pair >> 2;           // 0..31
    const int sbi  = pair & 3;            // 0..3
    const int s0 = sbi * BM;
    const int n0 = nb * BN;

    const int tx = threadIdx.x;
    const int lane = tx & 63;
    const int wid  = tx >> 6;
    const int wm = wid >> 2;          // 0..1  (128-row slab)
    const int wn = wid & 3;           // 0..3  (64-col slab)
    const int lr = lane & 15;
    const int lk = (lane >> 4) * 8;

    f32x4 acc[8][4];
    #pragma unroll
    for (int i = 0; i < 8; ++i)
        #pragma unroll
        for (int j = 0; j < 4; ++j) acc[i][j] = (f32x4){0.f, 0.f, 0.f, 0.f};

    const int arow = tx >> 1;
    const int akb  = (tx & 1) * 16;
    const int xk0 = tx >> 6;          // 0..7
    const int xn4 = (tx & 63) * 4;    // 0..252

    const float* ap = alphas + ((size_t)b * NS + s0 + arow) * NT + akb;
    const float* xp = x + ((size_t)b * NT + xk0) * ND + n0 + xn4;

    float4 va0 = reinterpret_cast<const float4*>(ap)[0];
    float4 va1 = reinterpret_cast<const float4*>(ap)[1];
    float4 va2 = reinterpret_cast<const float4*>(ap)[2];
    float4 va3 = reinterpret_cast<const float4*>(ap)[3];
    float4 vx0 = *reinterpret_cast<const float4*>(xp + 0 * 8 * ND);
    float4 vx1 = *reinterpret_cast<const float4*>(xp + 1 * 8 * ND);
    float4 vx2 = *reinterpret_cast<const float4*>(xp + 2 * 8 * ND);
    float4 vx3 = *reinterpret_cast<const float4*>(xp + 3 * 8 * ND);
    ap += BK;
    xp += (size_t)BK * ND;

    for (int k0 = 0; k0 < NT; k0 += BK) {
        {
            bf16x8 w0, w1;
            w0[0]=(__bf16)va0.x; w0[1]=(__bf16)va0.y; w0[2]=(__bf16)va0.z; w0[3]=(__bf16)va0.w;
            w0[4]=(__bf16)va1.x; w0[5]=(__bf16)va1.y; w0[6]=(__bf16)va1.z; w0[7]=(__bf16)va1.w;
            w1[0]=(__bf16)va2.x; w1[1]=(__bf16)va2.y; w1[2]=(__bf16)va2.z; w1[3]=(__bf16)va2.w;
            w1[4]=(__bf16)va3.x; w1[5]=(__bf16)va3.y; w1[6]=(__bf16)va3.z; w1[7]=(__bf16)va3.w;
            *reinterpret_cast<bf16x8*>(&As[arow * LDP + akb])     = w0;
            *reinterpret_cast<bf16x8*>(&As[arow * LDP + akb + 8]) = w1;
            Xs[(xn4+0)*LDP + xk0]      = (__bf16)vx0.x;
            Xs[(xn4+1)*LDP + xk0]      = (__bf16)vx0.y;
            Xs[(xn4+2)*LDP + xk0]      = (__bf16)vx0.z;
            Xs[(xn4+3)*LDP + xk0]      = (__bf16)vx0.w;
            Xs[(xn4+0)*LDP + xk0 + 8]  = (__bf16)vx1.x;
            Xs[(xn4+1)*LDP + xk0 + 8]  = (__bf16)vx1.y;
            Xs[(xn4+2)*LDP + xk0 + 8]  = (__bf16)vx1.z;
            Xs[(xn4+3)*LDP + xk0 + 8]  = (__bf16)vx1.w;
            Xs[(xn4+0)*LDP + xk0 + 16] = (__bf16)vx2.x;
            Xs[(xn4+1)*LDP + xk0 + 16] = (__bf16)vx2.y;
            Xs[(xn4+2)*LDP + xk0 + 16] = (__bf16)vx2.z;
            Xs[(xn4+3)*LDP + xk0 + 16] = (__bf16)vx2.w;
            Xs[(xn4+0)*LDP + xk0 + 24] = (__bf16)vx3.x;
            Xs[(xn4+1)*LDP + xk0 + 24] = (__bf16)vx3.y;
            Xs[(xn4+2)*LDP + xk0 + 24] = (__bf16)vx3.z;
            Xs[(xn4+3)*LDP + xk0 + 24] = (__bf16)vx3.w;
        }
        if (k0 + BK < NT) {
            va0 = reinterpret_cast<const float4*>(ap)[0];
            va1 = reinterpret_cast<const float4*>(ap)[1];
            va2 = reinterpret_cast<const float4*>(ap)[2];
            va3 = reinterpret_cast<const float4*>(ap)[3];
            vx0 = *reinterpret_cast<const float4*>(xp + 0 * 8 * ND);
            vx1 = *reinterpret_cast<const float4*>(xp + 1 * 8 * ND);
            vx2 = *reinterpret_cast<const float4*>(xp + 2 * 8 * ND);
            vx3 = *reinterpret_cast<const float4*>(xp + 3 * 8 * ND);
            ap += BK;
            xp += (size_t)BK * ND;
        }
        lds_barrier();   // lgkm-only — prefetch global loads stay in flight

        bf16x8 av[8], bv[4];
        #pragma unroll
        for (int j = 0; j < 4; ++j)
            bv[j] = *reinterpret_cast<const bf16x8*>(&Xs[(wn*64 + j*16 + lr) * LDP + lk]);
        #pragma unroll
        for (int i = 0; i < 8; ++i)
            av[i] = *reinterpret_cast<const bf16x8*>(&As[(wm*128 + i*16 + lr) * LDP + lk]);
        #pragma unroll
        for (int i = 0; i < 8; ++i)
            #pragma unroll
            for (int j = 0; j < 4; ++j)
                acc[i][j] = __builtin_amdgcn_mfma_f32_16x16x32_bf16(av[i], bv[j], acc[i][j], 0, 0, 0);
        lds_barrier();
    }

    const int ccol = lr;
    const int crow = (lane >> 4) * 4;
    #pragma unroll
    for (int i = 0; i < 8; ++i) {
        #pragma unroll
        for (int j = 0; j < 4; ++j) {
            int col = n0 + wn*64 + j*16 + ccol;
            int rw  = s0 + wm*128 + i*16 + crow;
            #pragma unroll
            for (int r = 0; r < 4; ++r)
                contexts[((size_t)b * NS + rw + r) * ND + col] = acc[i][j][r];
        }
    }
}

extern "C" void kernel_launch(void* const* d_in, const int* in_sizes, int n_in,
                              void* d_out, int out_size, void* d_ws, size_t ws_size,
                              hipStream_t stream) {
    const float* x    = (const float*)d_in[0];
    const float* W    = (const float*)d_in[1];
    const float* bias = (const float*)d_in[2];
    float* contexts = (float*)d_out;
    float* alphas   = (float*)d_out + CTX_ELEMS;
    float* sp       = (float*)d_out + SP_SCRATCH_OFF;

    sp_kernel<<<dim3(NB * NT / 4), dim3(256), 0, stream>>>(x, W, bias, sp);
    scan_kernel<<<dim3(NB), dim3(512), 0, stream>>>(sp, alphas);
    gemm_kernel<<<dim3(256), dim3(512), 0, stream>>>(alphas, x, contexts);
}

// Round 10
// 426.645 us; speedup vs baseline: 1.8170x; 1.1194x over previous
//
#include <hip/hip_runtime.h>
#include <hip/hip_bf16.h>

#define NB 32
#define NT 1024
#define ND 512
#define NS 1024

#define CTX_ELEMS (32u * 1024u * 512u)          // 16777216
#define SP_SCRATCH_OFF (CTX_ELEMS - 32u*1024u)  // stash sp in contexts tail (overwritten later)

__device__ __forceinline__ float vlog2(float x) {
    float r; asm("v_log_f32 %0, %1" : "=v"(r) : "v"(x)); return r;
}
__device__ __forceinline__ float vexp2(float x) {
    float r; asm("v_exp_f32 %0, %1" : "=v"(r) : "v"(x)); return r;
}
__device__ __forceinline__ float vrcp(float x) {
    float r; asm("v_rcp_f32 %0, %1" : "=v"(r) : "v"(x)); return r;
}

template<int ctrl, int rm, int bm, bool bc>
__device__ __forceinline__ float dppadd(float x) {
    int y = __builtin_amdgcn_update_dpp(0, __float_as_int(x), ctrl, rm, bm, bc);
    return x + __int_as_float(y);
}
// full-wave sum; valid result lands in lane 63
__device__ __forceinline__ float reduce63(float x) {
    x = dppadd<0x111, 0xf, 0xf, true >(x);   // row_shr:1
    x = dppadd<0x112, 0xf, 0xf, true >(x);   // row_shr:2
    x = dppadd<0x114, 0xf, 0xf, true >(x);   // row_shr:4
    x = dppadd<0x118, 0xf, 0xf, true >(x);   // row_shr:8
    x = dppadd<0x142, 0xa, 0xf, false>(x);   // row_bcast:15
    x = dppadd<0x143, 0xc, 0xf, false>(x);   // row_bcast:31
    return x;
}
// lane L receives x from lane L-1 (lane 0 gets 0)
__device__ __forceinline__ float wave_shr1(float x) {
    int y = __builtin_amdgcn_update_dpp(0, __float_as_int(x), 0x138, 0xf, 0xf, true);
    return __int_as_float(y);
}

// barrier that waits ONLY on LDS ops — global stores stay in flight
__device__ __forceinline__ void lds_barrier() {
    asm volatile("s_waitcnt lgkmcnt(0)" ::: "memory");
    __builtin_amdgcn_s_barrier();
    asm volatile("" ::: "memory");
}

// ---------------- kernel 1: sp[b][t] = sigmoid(dot(x[b,t,:], W) + bias) ----------------
__global__ __launch_bounds__(256) void sp_kernel(const float* __restrict__ x,
                                                 const float* __restrict__ W,
                                                 const float* __restrict__ bias,
                                                 float* __restrict__ sp)
{
    const int lane = threadIdx.x & 63;
    const int wid  = threadIdx.x >> 6;
    const int row  = blockIdx.x * 4 + wid;          // b*NT + t
    const float4* xr = reinterpret_cast<const float4*>(x + (size_t)row * ND) + lane * 2;
    const float4* wr = reinterpret_cast<const float4*>(W) + lane * 2;
    float4 xa = xr[0], xb = xr[1];
    float4 wa = wr[0], wb = wr[1];
    float d = xa.x*wa.x + xa.y*wa.y + xa.z*wa.z + xa.w*wa.w
            + xb.x*wb.x + xb.y*wb.y + xb.z*wb.z + xb.w*wb.w;
    #pragma unroll
    for (int m = 1; m < 64; m <<= 1) d += __shfl_xor(d, m);
    if (lane == 0) {
        float z = d + bias[0];
        float e = vexp2(-z * 1.442695040888963f);
        sp[row] = 1.0f / (1.0f + e);
    }
}

// ---------------- kernel 2: sequential scan, 4 waves per batch row ------
// R2 skeleton + three chain cuts:
//  (1) lagged store: row s-1 stored between publish and barrier (dead window)
//  (2) w-form: v = ((t1-t2)*a + t2*sh)*inv^2 + eps  — fmas run parallel with rcp
//  (3) peeled steps 0/1023, unroll x2, compile-time LDS slot
__global__ __launch_bounds__(256) void scan_kernel(const float* __restrict__ sp,
                                                   float* __restrict__ alphas)
{
    const int b    = blockIdx.x;
    const int tx   = threadIdx.x;
    const int lane = tx & 63;
    const int wid  = tx >> 6;

    __shared__ __align__(16) float4 xch[2][4];   // {p1, p2, boundary, pad} per wave

    float spv[4], raw[4], an[4], o[4];
    {
        float4 v = *reinterpret_cast<const float4*>(sp + (size_t)b * NT + tx * 4);
        spv[0] = v.x; spv[1] = v.y; spv[2] = v.z; spv[3] = v.w;
    }
    #pragma unroll
    for (int j = 0; j < 4; ++j) raw[j] = 1e-7f;
    if (tx == 0) raw[0] = 1.0f;
    float carry = (wid == 0) ? 0.0f : 1e-7f;

    // prologue: u0 = sum(alpha0_raw * sp)   (slot 1)
    {
        float q = fmaf(raw[0], spv[0], fmaf(raw[1], spv[1], fmaf(raw[2], spv[2], raw[3]*spv[3])));
        q = reduce63(q);
        if (lane == 63) xch[1][wid] = make_float4(q, 0.f, 0.f, 0.f);
    }
    lds_barrier();
    float u, inv, inv2, sq, cA, tt2;
    {
        float4 x0 = xch[1][0], x1 = xch[1][1], x2 = xch[1][2], x3 = xch[1][3];
        u = (x0.x + x1.x) + (x2.x + x3.x);
    }

    float* outp = alphas + (size_t)b * NS * NT + tx * 4;

    // ---- peel step 0 (inv = 1, c-form) -> publish slot 0 ----
    {
        sq = 1.7f - fabsf(u - 0.5f);
        const float c1 = 1.0f - u;
        const float c0 = u;
        float prev = wave_shr1(raw[3]);
        float sh0  = (lane == 0) ? carry : prev;
        an[0] = vexp2(sq * vlog2(fmaf(c1, raw[0], fmaf(c0, sh0,    1e-6f))));
        an[1] = vexp2(sq * vlog2(fmaf(c1, raw[1], fmaf(c0, raw[0], 1e-6f))));
        an[2] = vexp2(sq * vlog2(fmaf(c1, raw[2], fmaf(c0, raw[1], 1e-6f))));
        an[3] = vexp2(sq * vlog2(fmaf(c1, raw[3], fmaf(c0, raw[2], 1e-6f))));
        float p1 = (an[0] + an[1]) + (an[2] + an[3]);
        float p2 = fmaf(an[0], spv[0], an[1]*spv[1]) + fmaf(an[2], spv[2], an[3]*spv[3]);
        p1 = reduce63(p1);
        p2 = reduce63(p2);
        if (lane == 63) xch[0][wid] = make_float4(p1, p2, an[3], 0.f);
        lds_barrier();
        float4 x0 = xch[0][0], x1 = xch[0][1], x2 = xch[0][2], x3 = xch[0][3];
        float bc = (wid == 1) ? x0.z : (wid == 2) ? x1.z : (wid == 3) ? x2.z : 0.0f;
        carry = bc;
        float t1 = (x0.x + x1.x) + (x2.x + x3.x);
        float t2 = (x0.y + x1.y) + (x2.y + x3.y);
        inv  = vrcp(t1);
        inv2 = inv * inv;
        u    = t2 * inv;
        sq   = 1.7f - fabsf(u - 0.5f);
        cA   = t1 - t2;
        tt2  = t2;
        #pragma unroll
        for (int j = 0; j < 4; ++j) { o[j] = an[j] * inv; raw[j] = an[j]; }
    }

    // ---- main body: w-form step publishing to SLOT; stores previous row in window ----
#define STEPB(SLOT)                                                                     \
    do {                                                                                \
        float prev = wave_shr1(raw[3]);                                                 \
        float sh0  = (lane == 0) ? carry : prev;                                        \
        float w0 = fmaf(cA, raw[0], tt2 * sh0);                                         \
        float w1 = fmaf(cA, raw[1], tt2 * raw[0]);                                      \
        float w2 = fmaf(cA, raw[2], tt2 * raw[1]);                                      \
        float w3 = fmaf(cA, raw[3], tt2 * raw[2]);                                      \
        an[0] = vexp2(sq * vlog2(fmaf(w0, inv2, 1e-6f)));                               \
        an[1] = vexp2(sq * vlog2(fmaf(w1, inv2, 1e-6f)));                               \
        an[2] = vexp2(sq * vlog2(fmaf(w2, inv2, 1e-6f)));                               \
        an[3] = vexp2(sq * vlog2(fmaf(w3, inv2, 1e-6f)));                               \
        float p1 = (an[0] + an[1]) + (an[2] + an[3]);                                   \
        float p2 = fmaf(an[0], spv[0], an[1]*spv[1]) + fmaf(an[2], spv[2], an[3]*spv[3]);\
        p1 = reduce63(p1);                                                              \
        p2 = reduce63(p2);                                                              \
        if (lane == 63) xch[SLOT][wid] = make_float4(p1, p2, an[3], 0.f);               \
        { /* lagged store of row s-1 fills the barrier wait */                          \
            float4 ov; ov.x = o[0]; ov.y = o[1]; ov.z = o[2]; ov.w = o[3];              \
            *reinterpret_cast<float4*>(outp) = ov;                                      \
            outp += NT;                                                                 \
        }                                                                               \
        lds_barrier();                                                                  \
        float4 x0 = xch[SLOT][0], x1 = xch[SLOT][1], x2 = xch[SLOT][2], x3 = xch[SLOT][3];\
        float bc = (wid == 1) ? x0.z : (wid == 2) ? x1.z : (wid == 3) ? x2.z : 0.0f;    \
        carry = bc;                                                                     \
        float t1 = (x0.x + x1.x) + (x2.x + x3.x);                                       \
        float t2 = (x0.y + x1.y) + (x2.y + x3.y);                                       \
        inv  = vrcp(t1);                                                                \
        inv2 = inv * inv;                                                               \
        u    = t2 * inv;                                                                \
        sq   = 1.7f - fabsf(u - 0.5f);                                                  \
        cA   = t1 - t2;                                                                 \
        tt2  = t2;                                                                      \
        _Pragma("unroll")                                                               \
        for (int j = 0; j < 4; ++j) { o[j] = an[j] * inv; raw[j] = an[j]; }             \
    } while (0)

    // steps 1..1022 (511 x 2), alternating slots 1,0
    for (int s = 1; s <= 1021; s += 2) {
        STEPB(1);
        STEPB(0);
    }
    // step 1023 (slot 1)
    STEPB(1);
    // final store: row 1023
    {
        float4 ov; ov.x = o[0]; ov.y = o[1]; ov.z = o[2]; ov.w = o[3];
        *reinterpret_cast<float4*>(outp) = ov;
    }
#undef STEPB
}

// ---------------- kernel 3: contexts[b] = alphas[b] (SxT) @ x[b] (TxD), bf16 MFMA ------
// 256x256 tile, 512 threads = 8 waves (2 x 4), each wave owns 128x64.
// 1-D grid with XCD-pair swizzle: bids p and p+8 (same XCD under %8 round-robin)
// are the two n-tiles sharing one (b, s-block) A-panel -> A fetched once per L2.
typedef __bf16 bf16x8 __attribute__((ext_vector_type(8)));
typedef float  f32x4  __attribute__((ext_vector_type(4)));

#define BM 256
#define BN 256
#define BK 32
#define LDP 40   // padded leading dim (bf16 elems)

__global__ __launch_bounds__(512, 2) void gemm_kernel(const float* __restrict__ alphas,
                                                      const float* __restrict__ x,
                                                      float* __restrict__ contexts)
{
    __shared__ __align__(16) __bf16 As[BM * LDP];   // As[row][k]   20 KB
    __shared__ __align__(16) __bf16 Xs[BN * LDP];   // Xs[n][k]     20 KB (transposed)

    // XCD-pair decode
    const int bid  = blockIdx.x;
    const int low3 = bid & 7;
    const int slot = bid >> 3;            // 0..31
    const int nb   = slot & 1;
    const int pair = (slot >> 1) * 8 + low3;   // 0..127
    const int b    = pair >> 2;           // 0..31
    const int sbi  = pair & 3;            // 0..3
    const int s0 = sbi * BM;
    const int n0 = nb * BN;

    const int tx = threadIdx.x;
    const int lane = tx & 63;
    const int wid  = tx >> 6;
    const int wm = wid >> 2;          // 0..1  (128-row slab)
    const int wn = wid & 3;           // 0..3  (64-col slab)
    const int lr = lane & 15;
    const int lk = (lane >> 4) * 8;

    f32x4 acc[8][4];
    #pragma unroll
    for (int i = 0; i < 8; ++i)
        #pragma unroll
        for (int j = 0; j < 4; ++j) acc[i][j] = (f32x4){0.f, 0.f, 0.f, 0.f};

    const int arow = tx >> 1;
    const int akb  = (tx & 1) * 16;
    const int xk0 = tx >> 6;          // 0..7
    const int xn4 = (tx & 63) * 4;    // 0..252

    const float* ap = alphas + ((size_t)b * NS + s0 + arow) * NT + akb;
    const float* xp = x + ((size_t)b * NT + xk0) * ND + n0 + xn4;

    float4 va0 = reinterpret_cast<const float4*>(ap)[0];
    float4 va1 = reinterpret_cast<const float4*>(ap)[1];
    float4 va2 = reinterpret_cast<const float4*>(ap)[2];
    float4 va3 = reinterpret_cast<const float4*>(ap)[3];
    float4 vx0 = *reinterpret_cast<const float4*>(xp + 0 * 8 * ND);
    float4 vx1 = *reinterpret_cast<const float4*>(xp + 1 * 8 * ND);
    float4 vx2 = *reinterpret_cast<const float4*>(xp + 2 * 8 * ND);
    float4 vx3 = *reinterpret_cast<const float4*>(xp + 3 * 8 * ND);
    ap += BK;
    xp += (size_t)BK * ND;

    for (int k0 = 0; k0 < NT; k0 += BK) {
        {
            bf16x8 w0, w1;
            w0[0]=(__bf16)va0.x; w0[1]=(__bf16)va0.y; w0[2]=(__bf16)va0.z; w0[3]=(__bf16)va0.w;
            w0[4]=(__bf16)va1.x; w0[5]=(__bf16)va1.y; w0[6]=(__bf16)va1.z; w0[7]=(__bf16)va1.w;
            w1[0]=(__bf16)va2.x; w1[1]=(__bf16)va2.y; w1[2]=(__bf16)va2.z; w1[3]=(__bf16)va2.w;
            w1[4]=(__bf16)va3.x; w1[5]=(__bf16)va3.y; w1[6]=(__bf16)va3.z; w1[7]=(__bf16)va3.w;
            *reinterpret_cast<bf16x8*>(&As[arow * LDP + akb])     = w0;
            *reinterpret_cast<bf16x8*>(&As[arow * LDP + akb + 8]) = w1;
            Xs[(xn4+0)*LDP + xk0]      = (__bf16)vx0.x;
            Xs[(xn4+1)*LDP + xk0]      = (__bf16)vx0.y;
            Xs[(xn4+2)*LDP + xk0]      = (__bf16)vx0.z;
            Xs[(xn4+3)*LDP + xk0]      = (__bf16)vx0.w;
            Xs[(xn4+0)*LDP + xk0 + 8]  = (__bf16)vx1.x;
            Xs[(xn4+1)*LDP + xk0 + 8]  = (__bf16)vx1.y;
            Xs[(xn4+2)*LDP + xk0 + 8]  = (__bf16)vx1.z;
            Xs[(xn4+3)*LDP + xk0 + 8]  = (__bf16)vx1.w;
            Xs[(xn4+0)*LDP + xk0 + 16] = (__bf16)vx2.x;
            Xs[(xn4+1)*LDP + xk0 + 16] = (__bf16)vx2.y;
            Xs[(xn4+2)*LDP + xk0 + 16] = (__bf16)vx2.z;
            Xs[(xn4+3)*LDP + xk0 + 16] = (__bf16)vx2.w;
            Xs[(xn4+0)*LDP + xk0 + 24] = (__bf16)vx3.x;
            Xs[(xn4+1)*LDP + xk0 + 24] = (__bf16)vx3.y;
            Xs[(xn4+2)*LDP + xk0 + 24] = (__bf16)vx3.z;
            Xs[(xn4+3)*LDP + xk0 + 24] = (__bf16)vx3.w;
        }
        if (k0 + BK < NT) {
            va0 = reinterpret_cast<const float4*>(ap)[0];
            va1 = reinterpret_cast<const float4*>(ap)[1];
            va2 = reinterpret_cast<const float4*>(ap)[2];
            va3 = reinterpret_cast<const float4*>(ap)[3];
            vx0 = *reinterpret_cast<const float4*>(xp + 0 * 8 * ND);
            vx1 = *reinterpret_cast<const float4*>(xp + 1 * 8 * ND);
            vx2 = *reinterpret_cast<const float4*>(xp + 2 * 8 * ND);
            vx3 = *reinterpret_cast<const float4*>(xp + 3 * 8 * ND);
            ap += BK;
            xp += (size_t)BK * ND;
        }
        lds_barrier();   // lgkm-only — prefetch global loads stay in flight

        bf16x8 av[8], bv[4];
        #pragma unroll
        for (int j = 0; j < 4; ++j)
            bv[j] = *reinterpret_cast<const bf16x8*>(&Xs[(wn*64 + j*16 + lr) * LDP + lk]);
        #pragma unroll
        for (int i = 0; i < 8; ++i)
            av[i] = *reinterpret_cast<const bf16x8*>(&As[(wm*128 + i*16 + lr) * LDP + lk]);
        #pragma unroll
        for (int i = 0; i < 8; ++i)
            #pragma unroll
            for (int j = 0; j < 4; ++j)
                acc[i][j] = __builtin_amdgcn_mfma_f32_16x16x32_bf16(av[i], bv[j], acc[i][j], 0, 0, 0);
        lds_barrier();
    }

    const int ccol = lr;
    const int crow = (lane >> 4) * 4;
    #pragma unroll
    for (int i = 0; i < 8; ++i) {
        #pragma unroll
        for (int j = 0; j < 4; ++j) {
            int col = n0 + wn*64 + j*16 + ccol;
            int rw  = s0 + wm*128 + i*16 + crow;
            #pragma unroll
            for (int r = 0; r < 4; ++r)
                contexts[((size_t)b * NS + rw + r) * ND + col] = acc[i][j][r];
        }
    }
}

extern "C" void kernel_launch(void* const* d_in, const int* in_sizes, int n_in,
                              void* d_out, int out_size, void* d_ws, size_t ws_size,
                              hipStream_t stream) {
    const float* x    = (const float*)d_in[0];
    const float* W    = (const float*)d_in[1];
    const float* bias = (const float*)d_in[2];
    float* contexts = (float*)d_out;
    float* alphas   = (float*)d_out + CTX_ELEMS;
    float* sp       = (float*)d_out + SP_SCRATCH_OFF;

    sp_kernel<<<dim3(NB * NT / 4), dim3(256), 0, stream>>>(x, W, bias, sp);
    scan_kernel<<<dim3(NB), dim3(256), 0, stream>>>(sp, alphas);
    gemm_kernel<<<dim3(256), dim3(512), 0, stream>>>(alphas, x, contexts);
}